// Round 4
// baseline (130.106 us; speedup 1.0000x reference)
//
#include <hip/hip_runtime.h>

// Conv2d 3x3 s1 p1, N=16 C=64 H=W=112 F=64, fp32 in/out, bf16 MFMA implicit GEMM.
// R4: one block = 4 output rows; wave w owns output row h0+w ENTIRELY
// (7 M-tiles x 64 cout). Kills the 4x redundant LDS A-reads of R3 and cuts
// staging redundancy 3x -> 1.5x. B-frags double-buffer-prefetched from L2-hot
// pre-converted weight tensor; K-loop is MFMA-major (8 MFMA per 2 ds_read_b128).

typedef __attribute__((ext_vector_type(8))) short bf16x8;
typedef __attribute__((ext_vector_type(4))) float f32x4;

#define CIN 64
#define COUT 64
#define HH 112
#define WW 112
#define ROWS 4           // output rows per block
#define DYS  6           // staged input rows (ROWS + 2)

// LDS input tile: bf16 [6 rows][114 wcols][72 shorts (36 dwords; 32 used)]
// channel octet o at dword slot 4*(o ^ ((wcol>>2)&7))
#define XP 72
#define WCOLS 114
#define LDS_SHORTS (DYS * WCOLS * XP)   // 49248 shorts = 98496 B

__device__ __forceinline__ unsigned short f2bf(float f) {
    unsigned u = __builtin_bit_cast(unsigned, f);
    u += 0x7FFFu + ((u >> 16) & 1u);   // round-to-nearest-even
    return (unsigned short)(u >> 16);
}

// ---- one-time weight conversion: OIHW fp32 -> bf16 [t][cb][koct][f][j] ----
__global__ void conv_wprep(const float* __restrict__ w, short* __restrict__ wbf) {
    int i = blockIdx.x * 256 + threadIdx.x;    // grid sized to exactly 36864
    int j = i & 7;
    int f = (i >> 3) & 63;
    int koct = (i >> 9) & 3;
    int cb = (i >> 11) & 1;
    int t = i >> 12;
    int c = cb * 32 + koct * 8 + j;
    int ky = t / 3, kx = t - ky * 3;
    wbf[i] = (short)f2bf(w[((f * CIN + c) * 3 + ky) * 3 + kx]);
}

__global__ __launch_bounds__(256, 1)
void conv3x3_mfma(const float* __restrict__ x, const short* __restrict__ wbf,
                  const float* __restrict__ bias, float* __restrict__ out)
{
    __shared__ __align__(16) short lds[LDS_SHORTS];
    const int tid = threadIdx.x;
    const int n = blockIdx.x;
    const int h0 = blockIdx.y * ROWS;

    const int wave = tid >> 6;         // = output row within block
    const int lane = tid & 63;
    const int lm = lane & 15;          // A: pixel m ; B/D: cout col
    const int q  = lane >> 4;          // k-octet index 0..3

    // ---- zero the padding columns (wcol 0 and 113) for all 6 dy ----
    if (tid < 192) {
        int e = tid & 15;              // uint2 slot 0..15 (32 dwords)
        int g = tid >> 4;              // 0..11
        int dy = g >> 1;
        int wcol = (g & 1) ? (WCOLS - 1) : 0;
        *(uint2*)&lds[((dy * WCOLS + wcol) * 36 + e * 2) * 2] = (uint2){0u, 0u};
    }
    // ---- zero out-of-bounds input planes (only dy=0 at h0=0, dy=5 at h0=108)
    if (h0 == 0) {
        for (int i = tid; i < WCOLS * 16; i += 256) {
            int wcol = i >> 4, e = i & 15;
            *(uint2*)&lds[((0 * WCOLS + wcol) * 36 + e * 2) * 2] = (uint2){0u, 0u};
        }
    }
    if (h0 == HH - ROWS) {
        for (int i = tid; i < WCOLS * 16; i += 256) {
            int wcol = i >> 4, e = i & 15;
            *(uint2*)&lds[((5 * WCOLS + wcol) * 36 + e * 2) * 2] = (uint2){0u, 0u};
        }
    }
    // ---- stage interior: 6 dy x 16 c-quads x 28 w4-units ----
    for (int i = tid; i < DYS * 16 * 28; i += 256) {
        int w4 = i % 28;
        int rp = i / 28;               // 0..95
        int dy = rp >> 4;
        int cq = rp & 15;
        int gh = h0 + dy - 1;
        if ((unsigned)gh < (unsigned)HH) {
            int c = cq * 4;
            const float* px = x + (((n * CIN + c) * HH + gh) * WW + w4 * 4);
            const float4 v0 = *(const float4*)px;
            const float4 v1 = *(const float4*)(px + HH * WW);
            const float4 v2 = *(const float4*)(px + 2 * HH * WW);
            const float4 v3 = *(const float4*)(px + 3 * HH * WW);
            int o = cq >> 1, p = cq & 1;
            float a0[4] = {v0.x, v0.y, v0.z, v0.w};
            float a1[4] = {v1.x, v1.y, v1.z, v1.w};
            float a2[4] = {v2.x, v2.y, v2.z, v2.w};
            float a3[4] = {v3.x, v3.y, v3.z, v3.w};
#pragma unroll
            for (int dw = 0; dw < 4; ++dw) {
                int wcol = 1 + w4 * 4 + dw;
                int swz = (wcol >> 2) & 7;
                int dslot = 4 * (o ^ swz) + 2 * p;
                uint2 pk;
                pk.x = (unsigned)f2bf(a0[dw]) | ((unsigned)f2bf(a1[dw]) << 16);
                pk.y = (unsigned)f2bf(a2[dw]) | ((unsigned)f2bf(a3[dw]) << 16);
                *(uint2*)&lds[((dy * WCOLS + wcol) * 36 + dslot) * 2] = pk;
            }
        }
    }

    // ---- prefetch tap 0 B-fragments while staging drains ----
    // wbf layout: [t][cb][koct=q][f][j], addr = (t*8 + cb*4 + q)*512 + f*8 + j
    bf16x8 br[2][4][2];
#pragma unroll
    for (int nt = 0; nt < 4; ++nt) {
        br[0][nt][0] = *(const bf16x8*)(wbf + (0 * 8 + q) * 512 + (nt * 16 + lm) * 8);
        br[0][nt][1] = *(const bf16x8*)(wbf + (0 * 8 + 4 + q) * 512 + (nt * 16 + lm) * 8);
    }

    __syncthreads();

    f32x4 acc[7][4];
#pragma unroll
    for (int mt = 0; mt < 7; ++mt)
#pragma unroll
        for (int nt = 0; nt < 4; ++nt) acc[mt][nt] = (f32x4){0.f, 0.f, 0.f, 0.f};

#pragma unroll
    for (int t = 0; t < 9; ++t) {
        const int buf = t & 1;
        if (t < 8) {
#pragma unroll
            for (int nt = 0; nt < 4; ++nt) {
                br[1 - buf][nt][0] = *(const bf16x8*)(wbf + ((t + 1) * 8 + q) * 512 + (nt * 16 + lm) * 8);
                br[1 - buf][nt][1] = *(const bf16x8*)(wbf + ((t + 1) * 8 + 4 + q) * 512 + (nt * 16 + lm) * 8);
            }
        }
        const int ky = t / 3, kx = t - ky * 3;
#pragma unroll
        for (int mt = 0; mt < 7; ++mt) {
            int wcol = mt * 16 + lm + kx;           // 0..113
            int swz = (wcol >> 2) & 7;
            int base = ((wave + ky) * WCOLS + wcol) * XP;
            bf16x8 a0 = *(const bf16x8*)&lds[base + 8 * (q ^ swz)];
            bf16x8 a1 = *(const bf16x8*)&lds[base + 8 * ((q + 4) ^ swz)];
#pragma unroll
            for (int nt = 0; nt < 4; ++nt)
                acc[mt][nt] = __builtin_amdgcn_mfma_f32_16x16x32_bf16(a0, br[buf][nt][0], acc[mt][nt], 0, 0, 0);
#pragma unroll
            for (int nt = 0; nt < 4; ++nt)
                acc[mt][nt] = __builtin_amdgcn_mfma_f32_16x16x32_bf16(a1, br[buf][nt][1], acc[mt][nt], 0, 0, 0);
        }
    }

    // ---- epilogue: two cout-half passes through LDS, coalesced stores ----
    float* lout = (float*)lds;     // [4 waves][32 f][113 px] = 57856 floats
#pragma unroll
    for (int pass = 0; pass < 2; ++pass) {
        __syncthreads();
#pragma unroll
        for (int mt = 0; mt < 7; ++mt)
#pragma unroll
            for (int ntl = 0; ntl < 2; ++ntl) {
                const f32x4 v = acc[mt][pass * 2 + ntl];
#pragma unroll
                for (int r = 0; r < 4; ++r)
                    lout[(wave * 32 + ntl * 16 + lm) * 113 + mt * 16 + q * 4 + r] = v[r];
            }
        __syncthreads();
        for (int i = tid; i < 128 * 28; i += 256) {   // 14 iters
            int fr = i / 28;                          // 0..127: (row w, f-local)
            int w4 = i - fr * 28;
            int w = fr >> 5;
            int f = pass * 32 + (fr & 31);
            float b = bias[f];
            const float* lp = lout + fr * 113 + w4 * 4;
            float4 v;
            v.x = lp[0] + b; v.y = lp[1] + b; v.z = lp[2] + b; v.w = lp[3] + b;
            *(float4*)(out + (((n * COUT + f) * HH + h0 + w) * WW + w4 * 4)) = v;
        }
    }
}

extern "C" void kernel_launch(void* const* d_in, const int* in_sizes, int n_in,
                              void* d_out, int out_size, void* d_ws, size_t ws_size,
                              hipStream_t stream) {
    const float* x = (const float*)d_in[0];
    const float* w = (const float*)d_in[1];
    const float* b = (const float*)d_in[2];
    float* out = (float*)d_out;
    short* wbf = (short*)d_ws;   // 36864 shorts = 73728 B

    conv_wprep<<<144, 256, 0, stream>>>(w, wbf);   // 144*256 == 36864 exactly
    dim3 grid(16, HH / ROWS);  // (n, hblk): id%8==n%8 keeps row re-reads on one XCD
    conv3x3_mfma<<<grid, 256, 0, stream>>>(x, wbf, b, out);
}

// Round 5
// 123.928 us; speedup vs baseline: 1.0498x; 1.0498x over previous
//
#include <hip/hip_runtime.h>

// Conv2d 3x3 s1 p1, N=16 C=64 H=W=112 F=64, fp32 in/out, bf16 MFMA implicit GEMM.
// R5: ROWS=2/DYS=4 -> LDS 65.7 KB -> 2 blocks/CU resident (phase overlap across
// blocks, 2 waves/SIMD so ds_read issues under MFMA). Wave w owns (row w>>1,
// cout-half w&1): A-read redundancy 2x. Packed bf16 conversion in staging.

typedef __attribute__((ext_vector_type(8))) short bf16x8;
typedef __attribute__((ext_vector_type(4))) float f32x4;

#define CIN 64
#define COUT 64
#define HH 112
#define WW 112
#define ROWS 2           // output rows per block
#define DYS  4           // staged input rows (ROWS + 2)

// LDS input tile: bf16 [4 rows][114 wcols][72 shorts (36 dwords; 32 used)]
// channel octet o at dword slot 4*(o ^ ((wcol>>2)&7)); 36-dword pitch rotates
// banks by 4 per wcol.
#define XP 72
#define WCOLS 114
#define LDS_SHORTS (DYS * WCOLS * XP)   // 32832 shorts = 65664 B

__device__ __forceinline__ unsigned short f2bf(float f) {
    unsigned u = __builtin_bit_cast(unsigned, f);
    u += 0x7FFFu + ((u >> 16) & 1u);   // round-to-nearest-even
    return (unsigned short)(u >> 16);
}

#if __has_builtin(__builtin_amdgcn_cvt_pk_bf16_f32)
__device__ __forceinline__ unsigned pk2bf(float a, float b) {
    typedef __attribute__((ext_vector_type(2))) __bf16 bf16x2;
    bf16x2 r = __builtin_amdgcn_cvt_pk_bf16_f32(a, b);
    return __builtin_bit_cast(unsigned, r);
}
#else
__device__ __forceinline__ unsigned pk2bf(float a, float b) {
    return (unsigned)f2bf(a) | ((unsigned)f2bf(b) << 16);
}
#endif

// ---- one-time weight conversion: OIHW fp32 -> bf16 [t][cb][koct][f][j] ----
__global__ void conv_wprep(const float* __restrict__ w, short* __restrict__ wbf) {
    int i = blockIdx.x * 256 + threadIdx.x;    // grid sized to exactly 36864
    int j = i & 7;
    int f = (i >> 3) & 63;
    int koct = (i >> 9) & 3;
    int cb = (i >> 11) & 1;
    int t = i >> 12;
    int c = cb * 32 + koct * 8 + j;
    int ky = t / 3, kx = t - ky * 3;
    wbf[i] = (short)f2bf(w[((f * CIN + c) * 3 + ky) * 3 + kx]);
}

__global__ __launch_bounds__(256, 2)
void conv3x3_mfma(const float* __restrict__ x, const short* __restrict__ wbf,
                  const float* __restrict__ bias, float* __restrict__ out)
{
    __shared__ __align__(16) short lds[LDS_SHORTS];
    const int tid = threadIdx.x;
    const int n = blockIdx.x;
    const int h0 = blockIdx.y * ROWS;

    const int wave = tid >> 6;
    const int r  = wave >> 1;          // output row within block (0..1)
    const int nh = wave & 1;           // cout half (0..1)
    const int lane = tid & 63;
    const int lm = lane & 15;          // A: pixel m ; B/D: cout col
    const int q  = lane >> 4;          // k-octet index 0..3

    // ---- zero the padding columns (wcol 0 and 113) for all 4 dy ----
    if (tid < 128) {
        int e = tid & 15;              // uint2 slot 0..15 (32 dwords)
        int g = tid >> 4;              // 0..7
        int dy = g >> 1;
        int wcol = (g & 1) ? (WCOLS - 1) : 0;
        *(uint2*)&lds[((dy * WCOLS + wcol) * 36 + e * 2) * 2] = (uint2){0u, 0u};
    }
    // ---- zero out-of-bounds input planes ----
    if (h0 == 0) {
        for (int i = tid; i < WCOLS * 16; i += 256) {
            int wcol = i >> 4, e = i & 15;
            *(uint2*)&lds[((0 * WCOLS + wcol) * 36 + e * 2) * 2] = (uint2){0u, 0u};
        }
    }
    if (h0 == HH - ROWS) {
        for (int i = tid; i < WCOLS * 16; i += 256) {
            int wcol = i >> 4, e = i & 15;
            *(uint2*)&lds[(((DYS - 1) * WCOLS + wcol) * 36 + e * 2) * 2] = (uint2){0u, 0u};
        }
    }
    // ---- stage interior: 4 dy x 16 c-quads x 28 w4-units (7 per thread) ----
    for (int i = tid; i < DYS * 16 * 28; i += 256) {
        int w4 = i % 28;
        int rp = i / 28;               // 0..63
        int dy = rp >> 4;
        int cq = rp & 15;
        int gh = h0 + dy - 1;
        if ((unsigned)gh < (unsigned)HH) {
            int c = cq * 4;
            const float* px = x + (((n * CIN + c) * HH + gh) * WW + w4 * 4);
            const float4 v0 = *(const float4*)px;
            const float4 v1 = *(const float4*)(px + HH * WW);
            const float4 v2 = *(const float4*)(px + 2 * HH * WW);
            const float4 v3 = *(const float4*)(px + 3 * HH * WW);
            int o = cq >> 1, p = cq & 1;
            float a0[4] = {v0.x, v0.y, v0.z, v0.w};
            float a1[4] = {v1.x, v1.y, v1.z, v1.w};
            float a2[4] = {v2.x, v2.y, v2.z, v2.w};
            float a3[4] = {v3.x, v3.y, v3.z, v3.w};
#pragma unroll
            for (int dw = 0; dw < 4; ++dw) {
                int wcol = 1 + w4 * 4 + dw;
                int swz = (wcol >> 2) & 7;
                int dslot = 4 * (o ^ swz) + 2 * p;
                uint2 pk;
                pk.x = pk2bf(a0[dw], a1[dw]);
                pk.y = pk2bf(a2[dw], a3[dw]);
                *(uint2*)&lds[((dy * WCOLS + wcol) * 36 + dslot) * 2] = pk;
            }
        }
    }

    // ---- prefetch tap 0 B-fragments while staging drains ----
    // wbf layout: [t][cb][koct=q][f][j], addr = (t*8 + cb*4 + q)*512 + f*8 + j
    bf16x8 br[2][2][2];                // [buf][ntl][cb]
#pragma unroll
    for (int ntl = 0; ntl < 2; ++ntl) {
        int f = (nh * 2 + ntl) * 16 + lm;
        br[0][ntl][0] = *(const bf16x8*)(wbf + (q) * 512 + f * 8);
        br[0][ntl][1] = *(const bf16x8*)(wbf + (4 + q) * 512 + f * 8);
    }

    __syncthreads();

    f32x4 acc[7][2];
#pragma unroll
    for (int mt = 0; mt < 7; ++mt)
#pragma unroll
        for (int ntl = 0; ntl < 2; ++ntl) acc[mt][ntl] = (f32x4){0.f, 0.f, 0.f, 0.f};

#pragma unroll
    for (int t = 0; t < 9; ++t) {
        const int buf = t & 1;
        if (t < 8) {
#pragma unroll
            for (int ntl = 0; ntl < 2; ++ntl) {
                int f = (nh * 2 + ntl) * 16 + lm;
                br[1 - buf][ntl][0] = *(const bf16x8*)(wbf + ((t + 1) * 8 + q) * 512 + f * 8);
                br[1 - buf][ntl][1] = *(const bf16x8*)(wbf + ((t + 1) * 8 + 4 + q) * 512 + f * 8);
            }
        }
        const int ky = t / 3, kx = t - ky * 3;
#pragma unroll
        for (int mt = 0; mt < 7; ++mt) {
            int wcol = mt * 16 + lm + kx;           // 0..113
            int swz = (wcol >> 2) & 7;
            int base = ((r + ky) * WCOLS + wcol) * XP;
            bf16x8 a0 = *(const bf16x8*)&lds[base + 8 * (q ^ swz)];
            bf16x8 a1 = *(const bf16x8*)&lds[base + 8 * ((q + 4) ^ swz)];
#pragma unroll
            for (int ntl = 0; ntl < 2; ++ntl)
                acc[mt][ntl] = __builtin_amdgcn_mfma_f32_16x16x32_bf16(a0, br[buf][ntl][0], acc[mt][ntl], 0, 0, 0);
#pragma unroll
            for (int ntl = 0; ntl < 2; ++ntl)
                acc[mt][ntl] = __builtin_amdgcn_mfma_f32_16x16x32_bf16(a1, br[buf][ntl][1], acc[mt][ntl], 0, 0, 0);
        }
    }

    // ---- epilogue: single pass through LDS, coalesced fp32 stores ----
    __syncthreads();
    float* lout = (float*)lds;     // [2 rows][64 f][113 px] = 57856 floats
#pragma unroll
    for (int mt = 0; mt < 7; ++mt)
#pragma unroll
        for (int ntl = 0; ntl < 2; ++ntl) {
            const f32x4 v = acc[mt][ntl];
            int fr = r * 64 + (nh * 2 + ntl) * 16 + lm;
#pragma unroll
            for (int rr = 0; rr < 4; ++rr)
                lout[fr * 113 + mt * 16 + q * 4 + rr] = v[rr];
        }
    __syncthreads();
    for (int i = tid; i < 128 * 28; i += 256) {   // 14 iters
        int fr = i / 28;                          // 0..127: (row, f)
        int w4 = i - fr * 28;
        int rw = fr >> 6;
        int f = fr & 63;
        float b = bias[f];
        const float* lp = lout + fr * 113 + w4 * 4;
        float4 v;
        v.x = lp[0] + b; v.y = lp[1] + b; v.z = lp[2] + b; v.w = lp[3] + b;
        *(float4*)(out + (((n * COUT + f) * HH + h0 + rw) * WW + w4 * 4)) = v;
    }
}

extern "C" void kernel_launch(void* const* d_in, const int* in_sizes, int n_in,
                              void* d_out, int out_size, void* d_ws, size_t ws_size,
                              hipStream_t stream) {
    const float* x = (const float*)d_in[0];
    const float* w = (const float*)d_in[1];
    const float* b = (const float*)d_in[2];
    float* out = (float*)d_out;
    short* wbf = (short*)d_ws;   // 36864 shorts = 73728 B

    conv_wprep<<<144, 256, 0, stream>>>(w, wbf);   // 144*256 == 36864 exactly
    dim3 grid(16, HH / ROWS);  // (n, hblk): id%8==n%8 keeps row re-reads on one XCD
    conv3x3_mfma<<<grid, 256, 0, stream>>>(x, wbf, b, out);
}